// Round 1
// 1241.002 us; speedup vs baseline: 1.0150x; 1.0150x over previous
//
#include <hip/hip_runtime.h>

// Problem constants (fixed by reference): B=64, S=2048, UNITS=1024
#define BB   64
#define SS   2048
#define UU   1024
#define MM   (BB * SS)          // 131072 rows of the big GEMM

typedef unsigned short u16;
typedef unsigned int   u32;
typedef __attribute__((ext_vector_type(8))) short bf16x8;
typedef __attribute__((ext_vector_type(4))) float f32x4;

__device__ __forceinline__ u16 f2b(float f) {
    // round-to-nearest-even fp32 -> bf16
    u32 x = __float_as_uint(f);
    u32 r = (x + 0x7fffu + ((x >> 16) & 1u)) >> 16;
    return (u16)r;
}
__device__ __forceinline__ float b2f(u16 u) {
    return __uint_as_float(((u32)u) << 16);
}
__device__ __forceinline__ float fast_tanh(float x) {
    x = fminf(fmaxf(x, -15.f), 15.f);
    float e = __expf(2.f * x);
    return (e - 1.f) / (e + 1.f);
}
// async global->LDS 16B per lane; LDS dest = wave-uniform base + lane*16
__device__ __forceinline__ void async_copy16(const u16* gp, u16* lp) {
    __builtin_amdgcn_global_load_lds(
        (const __attribute__((address_space(1))) unsigned int*)gp,
        (__attribute__((address_space(3))) unsigned int*)lp, 16, 0, 0);
}

#define WAITV(N) asm volatile("s_waitcnt vmcnt(" #N ")" ::: "memory")

// ---------------- kernel 1: U_w [k][n] fp32 -> U_wT [n][k] bf16 ----------------
__global__ __launch_bounds__(256) void k_transpose_uw(const float* __restrict__ Uw,
                                                      u16* __restrict__ UwT) {
    __shared__ float tile[64][65];
    int n0 = blockIdx.x * 64, k0 = blockIdx.y * 64;
    int c = threadIdx.x & 63, r0 = threadIdx.x >> 6;   // r0 in 0..3
#pragma unroll
    for (int i = 0; i < 64; i += 4)
        tile[r0 + i][c] = Uw[(size_t)(k0 + r0 + i) * UU + n0 + c];
    __syncthreads();
#pragma unroll
    for (int i = 0; i < 64; i += 4)
        UwT[(size_t)(n0 + r0 + i) * UU + k0 + c] = f2b(tile[c][r0 + i]);
}

// ---------------- kernel 2: h fp32 -> bf16 ----------------
__global__ __launch_bounds__(256) void k_convert_h(const float* __restrict__ src,
                                                   u16* __restrict__ dst) {
    size_t i = ((size_t)blockIdx.x * 256 + threadIdx.x) * 8;
    float4 f0 = *(const float4*)(src + i);
    float4 f1 = *(const float4*)(src + i + 4);
    u16 t[8];
    t[0] = f2b(f0.x); t[1] = f2b(f0.y); t[2] = f2b(f0.z); t[3] = f2b(f0.w);
    t[4] = f2b(f1.x); t[5] = f2b(f1.y); t[6] = f2b(f1.z); t[7] = f2b(f1.w);
    *(uint4*)(dst + i) = *(uint4*)t;
}

// ---------------- kernel 3: Ws = s_prev @ W_w + W_b (fp32), split-K atomic ----
__global__ __launch_bounds__(256) void k_ws(const float* __restrict__ sp,
                                            const float* __restrict__ Ww,
                                            const float* __restrict__ Wb,
                                            float* __restrict__ Ws) {
    int u = blockIdx.x * 256 + threadIdx.x;   // 0..1023
    int b = blockIdx.y;
    int k0 = blockIdx.z * 256;
    const float* sprow = sp + (size_t)b * UU + k0;
    float acc = (blockIdx.z == 0) ? Wb[u] : 0.f;
#pragma unroll 4
    for (int k = 0; k < 256; ++k)
        acc = fmaf(sprow[k], Ww[(size_t)(k0 + k) * UU + u], acc);
    atomicAdd(&Ws[(size_t)b * UU + u], acc);
}

// ---------------- kernel 4: 256^2-tile deep-pipelined GEMM + tanh*V_w reduce --
// 512 threads (8 waves: 2M x 4N), BK=32, 4 LDS buffers, depth-3 K-tile prefetch.
// Counted vmcnt (never 0 in steady state), 1 barrier per K-tile, setprio on MFMA.
// Grid 2048 = 512 m-tiles x 4 n-tiles; XCD swizzle: the 4 n-tiles of an m-tile
// share one XCD so the 512KB A-panel is L2-resident across them.
__global__ __launch_bounds__(512, 2) void k_gemm256(const u16* __restrict__ A,
                                                    const u16* __restrict__ UwT,
                                                    const float* __restrict__ Ws,
                                                    const float* __restrict__ Ub,
                                                    const float* __restrict__ Vw,
                                                    float* __restrict__ scp) {
    // 4 buffers x [256 rows x 32 bf16] for each of A,B = 128 KB total
    __shared__ __align__(16) u16 As[4][8192];
    __shared__ __align__(16) u16 Bs[4][8192];
    const int tid  = threadIdx.x;
    const int lane = tid & 63;
    const int wave = tid >> 6;            // 0..7
    const int wm = wave >> 2;             // 0..1 : M half (128 rows)
    const int wn = wave & 3;              // 0..3 : N quarter (64 cols)
    const int quad = lane >> 4, l15 = lane & 15;

    const int bid = blockIdx.x;
    const int xcd = bid & 7;
    const int li  = bid >> 3;             // 0..255 per XCD
    const int mt  = xcd * 64 + (li >> 2); // 0..511
    const int nt  = li & 3;               // 0..3
    const size_t m0 = (size_t)mt * 256;
    const int n0  = nt * 256;

    // staging lane geometry: 64 lanes cover one 16-row x 32-col group (1 KB).
    // LDS slot (srow, spos) must hold global chunk spos ^ ((srow>>1)&3)
    // (inverse-swizzled SOURCE, linear DEST -- global_load_lds constraint).
    const int srow   = lane >> 2;                       // 0..15
    const int schunk = (lane & 3) ^ ((srow >> 1) & 3);  // 16B chunk to fetch
    const size_t lane_off = (size_t)srow * UU + (size_t)schunk * 8;
    const int gA = wave * 2;              // this wave's two groups per tile

    // fragment LDS offsets (u16 units), constant across K-tiles.
    // read-side swizzle: pos = quad ^ ((row>>1)&3) -> 2 lanes/bank (free).
    int offA[8], offB[4];
#pragma unroll
    for (int mi = 0; mi < 8; ++mi) {
        int r = wm * 128 + mi * 16 + l15;
        offA[mi] = r * 32 + (quad ^ ((r >> 1) & 3)) * 8;
    }
#pragma unroll
    for (int ni = 0; ni < 4; ++ni) {
        int r = wn * 64 + ni * 16 + l15;
        offB[ni] = r * 32 + (quad ^ ((r >> 1) & 3)) * 8;
    }

    f32x4 acc[8][4];
#pragma unroll
    for (int i = 0; i < 8; ++i)
#pragma unroll
        for (int j = 0; j < 4; ++j) acc[i][j] = (f32x4){0.f, 0.f, 0.f, 0.f};

    const u16* Abase = A + m0 * UU;
    const u16* Bbase = UwT + (size_t)n0 * UU;

#define STAGE(kt) do {                                                         \
        const int _b = (kt) & 3;                                               \
        const u16* _ga = Abase + (size_t)(gA * 16) * UU + (kt) * 32 + lane_off;\
        async_copy16(_ga,                  &As[_b][gA * 512]);                 \
        async_copy16(_ga + (size_t)16 * UU, &As[_b][(gA + 1) * 512]);          \
        const u16* _gb = Bbase + (size_t)(gA * 16) * UU + (kt) * 32 + lane_off;\
        async_copy16(_gb,                  &Bs[_b][gA * 512]);                 \
        async_copy16(_gb + (size_t)16 * UU, &Bs[_b][(gA + 1) * 512]);          \
    } while (0)

    auto compute = [&](int kt) {
        const u16* ab = As[kt & 3];
        const u16* bb = Bs[kt & 3];
        bf16x8 a[8], b[4];
#pragma unroll
        for (int mi = 0; mi < 8; ++mi) a[mi] = *(const bf16x8*)(ab + offA[mi]);
#pragma unroll
        for (int ni = 0; ni < 4; ++ni) b[ni] = *(const bf16x8*)(bb + offB[ni]);
        __builtin_amdgcn_s_setprio(1);
#pragma unroll
        for (int mi = 0; mi < 8; ++mi)
#pragma unroll
            for (int ni = 0; ni < 4; ++ni)
                acc[mi][ni] = __builtin_amdgcn_mfma_f32_16x16x32_bf16(
                    a[mi], b[ni], acc[mi][ni], 0, 0, 0);
        __builtin_amdgcn_s_setprio(0);
    };

    // prologue: 3 K-tiles in flight (12 loads/thread)
    STAGE(0); STAGE(1); STAGE(2);

    // steady state: wait oldest tile (8 = 2 tiles x 4 loads still in flight),
    // barrier (all waves' loads landed AND all waves done reading the buffer
    // we are about to overwrite), then prefetch kt+3 and compute kt.
    for (int kt = 0; kt < 29; ++kt) {
        WAITV(8);
        __builtin_amdgcn_sched_barrier(0);
        __builtin_amdgcn_s_barrier();
        STAGE(kt + 3);
        compute(kt);
    }
    // epilogue drain: 8 -> 4 -> 0
    WAITV(8); __builtin_amdgcn_sched_barrier(0); __builtin_amdgcn_s_barrier(); compute(29);
    WAITV(4); __builtin_amdgcn_sched_barrier(0); __builtin_amdgcn_s_barrier(); compute(30);
    WAITV(0); __builtin_amdgcn_sched_barrier(0); __builtin_amdgcn_s_barrier(); compute(31);
#undef STAGE

    // ---- epilogue: score partial = sum_n tanh(acc + Ws[b][n] + Ub[n]) * Vw[n] ----
    const int bidx = (int)(m0 >> 11);            // 256-row m-tile lies in one batch
    const float* wsrow = Ws + (size_t)bidx * UU;
    float wsv[4], ubv[4], vwv[4];
#pragma unroll
    for (int ni = 0; ni < 4; ++ni) {
        int ng = n0 + wn * 64 + ni * 16 + l15;
        wsv[ni] = wsrow[ng];
        ubv[ni] = Ub[ng];
        vwv[ni] = Vw[ng];
    }
#pragma unroll
    for (int mi = 0; mi < 8; ++mi) {
#pragma unroll
        for (int r = 0; r < 4; ++r) {
            float v = 0.f;
#pragma unroll
            for (int ni = 0; ni < 4; ++ni) {
                float x = acc[mi][ni][r] + wsv[ni] + ubv[ni];
                v = fmaf(fast_tanh(x), vwv[ni], v);
            }
#pragma unroll
            for (int off = 1; off < 16; off <<= 1)
                v += __shfl_xor(v, off, 64);
            if (l15 == 0) {
                size_t mg = m0 + wm * 128 + mi * 16 + quad * 4 + r;
                scp[mg * 16 + nt * 4 + wn] = v;
            }
        }
    }
}

// ---------------- kernel 4b: fp32-input fallback (ws too small for hbf) -------
__global__ __launch_bounds__(256) void k_gemm_f32(const float* __restrict__ Aptr,
                                                  const u16* __restrict__ UwT,
                                                  const float* __restrict__ Ws,
                                                  const float* __restrict__ Ub,
                                                  const float* __restrict__ Vw,
                                                  float* __restrict__ scp) {
    __shared__ __align__(16) u16 As[128][72];
    __shared__ __align__(16) u16 Bs[128][72];
    const int tid  = threadIdx.x;
    const int lane = tid & 63;
    const int wave = tid >> 6;
    const int wm = wave >> 1, wn = wave & 1;
    const int quad = lane >> 4, l15 = lane & 15;
    const int nt = blockIdx.x;
    const int n0 = nt * 128;
    const size_t m0 = (size_t)blockIdx.y * 128;

    f32x4 acc[4][4];
#pragma unroll
    for (int i = 0; i < 4; ++i)
#pragma unroll
        for (int j = 0; j < 4; ++j) acc[i][j] = (f32x4){0.f, 0.f, 0.f, 0.f};

    const int sr = tid >> 3;
    const int sc = (tid & 7) * 8;

    for (int kk = 0; kk < UU; kk += 64) {
#pragma unroll
        for (int i = 0; i < 4; ++i) {
            int r = sr + i * 32;
            const float4* p = (const float4*)(Aptr + (m0 + r) * UU + kk + sc);
            float4 f0 = p[0], f1 = p[1];
            u16 t[8];
            t[0] = f2b(f0.x); t[1] = f2b(f0.y); t[2] = f2b(f0.z); t[3] = f2b(f0.w);
            t[4] = f2b(f1.x); t[5] = f2b(f1.y); t[6] = f2b(f1.z); t[7] = f2b(f1.w);
            *(uint4*)(&As[r][sc]) = *(uint4*)t;
        }
#pragma unroll
        for (int i = 0; i < 4; ++i) {
            int r = sr + i * 32;
            uint4 v = *(const uint4*)(UwT + (size_t)(n0 + r) * UU + kk + sc);
            *(uint4*)(&Bs[r][sc]) = v;
        }
        __syncthreads();
#pragma unroll
        for (int k2 = 0; k2 < 64; k2 += 32) {
            bf16x8 a[4], b[4];
#pragma unroll
            for (int mi = 0; mi < 4; ++mi)
                a[mi] = *(const bf16x8*)(&As[wm * 64 + mi * 16 + l15][k2 + quad * 8]);
#pragma unroll
            for (int ni = 0; ni < 4; ++ni)
                b[ni] = *(const bf16x8*)(&Bs[wn * 64 + ni * 16 + l15][k2 + quad * 8]);
#pragma unroll
            for (int mi = 0; mi < 4; ++mi)
#pragma unroll
                for (int ni = 0; ni < 4; ++ni)
                    acc[mi][ni] = __builtin_amdgcn_mfma_f32_16x16x32_bf16(
                        a[mi], b[ni], acc[mi][ni], 0, 0, 0);
        }
        __syncthreads();
    }

    const int bidx = (int)(m0 >> 11);
    const float* wsrow = Ws + (size_t)bidx * UU;
    float wsv[4], ubv[4], vwv[4];
#pragma unroll
    for (int ni = 0; ni < 4; ++ni) {
        int ng = n0 + wn * 64 + ni * 16 + l15;
        wsv[ni] = wsrow[ng];
        ubv[ni] = Ub[ng];
        vwv[ni] = Vw[ng];
    }
#pragma unroll
    for (int mi = 0; mi < 4; ++mi) {
#pragma unroll
        for (int r = 0; r < 4; ++r) {
            float v = 0.f;
#pragma unroll
            for (int ni = 0; ni < 4; ++ni) {
                float x = acc[mi][ni][r] + wsv[ni] + ubv[ni];
                v = fmaf(fast_tanh(x), vwv[ni], v);
            }
#pragma unroll
            for (int off = 1; off < 16; off <<= 1)
                v += __shfl_xor(v, off, 64);
            if (l15 == 0) {
                size_t mg = m0 + wm * 64 + mi * 16 + quad * 4 + r;
                scp[mg * 16 + nt * 2 + wn] = v;
            }
        }
    }
}

// ---------------- kernel 5: softmax over S per batch ----------------
__global__ __launch_bounds__(256) void k_softmax(const float* __restrict__ scp,
                                                 float* __restrict__ wout) {
    int b = blockIdx.x, t = threadIdx.x;
    __shared__ float red[256];
    float sc[8];
    float lmax = -1e30f;
#pragma unroll
    for (int i = 0; i < 8; ++i) {
        int s = t + i * 256;
        const float4* p = (const float4*)(scp + ((size_t)b * SS + s) * 16);
        float4 a = p[0], c = p[1], d = p[2], e = p[3];
        float v = (a.x + a.y + a.z + a.w) + (c.x + c.y + c.z + c.w) +
                  (d.x + d.y + d.z + d.w) + (e.x + e.y + e.z + e.w);
        sc[i] = v;
        lmax = fmaxf(lmax, v);
    }
    red[t] = lmax;
    __syncthreads();
    for (int o = 128; o > 0; o >>= 1) {
        if (t < o) red[t] = fmaxf(red[t], red[t + o]);
        __syncthreads();
    }
    float mx = red[0];
    __syncthreads();
    float lsum = 0.f;
#pragma unroll
    for (int i = 0; i < 8; ++i) {
        sc[i] = __expf(sc[i] - mx);
        lsum += sc[i];
    }
    red[t] = lsum;
    __syncthreads();
    for (int o = 128; o > 0; o >>= 1) {
        if (t < o) red[t] += red[t + o];
        __syncthreads();
    }
    float inv = 1.f / red[0];
#pragma unroll
    for (int i = 0; i < 8; ++i)
        wout[(size_t)b * SS + t + i * 256] = sc[i] * inv;
}

// ---------------- kernel 6: context = sum_s w[b][s] * h[b][s][:] ----------------
template <bool HBF16>
__global__ __launch_bounds__(256) void k_context(const void* __restrict__ hptr,
                                                 const float* __restrict__ w,
                                                 float* __restrict__ ctx) {
    int b = blockIdx.y;
    int s0 = blockIdx.x * 128;
    int u = threadIdx.x * 4;
    const float* wrow = w + (size_t)b * SS + s0;
    float a0 = 0.f, a1 = 0.f, a2 = 0.f, a3 = 0.f;
    for (int i = 0; i < 128; ++i) {
        float wv = wrow[i];
        size_t base = ((size_t)b * SS + s0 + i) * UU + u;
        if (HBF16) {
            ushort4 hv = *(const ushort4*)((const u16*)hptr + base);
            a0 = fmaf(wv, b2f(hv.x), a0);
            a1 = fmaf(wv, b2f(hv.y), a1);
            a2 = fmaf(wv, b2f(hv.z), a2);
            a3 = fmaf(wv, b2f(hv.w), a3);
        } else {
            float4 hv = *(const float4*)((const float*)hptr + base);
            a0 = fmaf(wv, hv.x, a0);
            a1 = fmaf(wv, hv.y, a1);
            a2 = fmaf(wv, hv.z, a2);
            a3 = fmaf(wv, hv.w, a3);
        }
    }
    atomicAdd(&ctx[(size_t)b * UU + u + 0], a0);
    atomicAdd(&ctx[(size_t)b * UU + u + 1], a1);
    atomicAdd(&ctx[(size_t)b * UU + u + 2], a2);
    atomicAdd(&ctx[(size_t)b * UU + u + 3], a3);
}

extern "C" void kernel_launch(void* const* d_in, const int* in_sizes, int n_in,
                              void* d_out, int out_size, void* d_ws, size_t ws_size,
                              hipStream_t stream) {
    const float* s_prev = (const float*)d_in[0];
    const float* h      = (const float*)d_in[1];
    const float* Ww     = (const float*)d_in[2];
    const float* Wb     = (const float*)d_in[3];
    const float* Uw     = (const float*)d_in[4];
    const float* Ub     = (const float*)d_in[5];
    const float* Vw     = (const float*)d_in[6];
    // d_in[7] = V_b: softmax(x + c) == softmax(x) -> V_b cancels in both outputs.

    float* out = (float*)d_out;                 // [0,65536): context  [65536,196608): weights
    char* ws = (char*)d_ws;

    // workspace layout
    u16*   UwT = (u16*)ws;                                        // 2 MB
    float* Ws  = (float*)(ws + (size_t)(2 << 20));                // 256 KB
    float* scp = (float*)(ws + (size_t)(2 << 20) + (256 << 10));  // 131072*16*4 = 8 MB
    size_t offH = (size_t)(2 << 20) + (256 << 10) + ((size_t)8 << 20);
    u16*   hbf = (u16*)(ws + offH);
    const size_t hBytes = (size_t)MM * UU * 2;  // 256 MB
    const bool useBf16 = (ws_size >= offH + hBytes);

    // zero atomically-accumulated buffers
    hipMemsetAsync(out, 0, (size_t)BB * UU * sizeof(float), stream);
    hipMemsetAsync(Ws, 0, (size_t)BB * UU * sizeof(float), stream);

    k_transpose_uw<<<dim3(16, 16), 256, 0, stream>>>(Uw, UwT);
    k_ws<<<dim3(4, BB, 4), 256, 0, stream>>>(s_prev, Ww, Wb, Ws);

    if (useBf16) {
        k_convert_h<<<(MM * (UU / 8)) / 256, 256, 0, stream>>>(h, hbf);
        k_gemm256<<<2048, 512, 0, stream>>>(hbf, UwT, Ws, Ub, Vw, scp);
    } else {
        k_gemm_f32<<<dim3(8, MM / 128), 256, 0, stream>>>(h, UwT, Ws, Ub, Vw, scp);
    }

    k_softmax<<<BB, 256, 0, stream>>>(scp, out + (size_t)BB * UU);

    if (useBf16)
        k_context<true><<<dim3(16, BB), 256, 0, stream>>>(hbf, out + (size_t)BB * UU, out);
    else
        k_context<false><<<dim3(16, BB), 256, 0, stream>>>(h, out + (size_t)BB * UU, out);
}

// Round 2
// 1191.083 us; speedup vs baseline: 1.0575x; 1.0419x over previous
//
#include <hip/hip_runtime.h>

// Problem constants (fixed by reference): B=64, S=2048, UNITS=1024
#define BB   64
#define SS   2048
#define UU   1024
#define MM   (BB * SS)          // 131072 rows of the big GEMM

typedef unsigned short u16;
typedef unsigned int   u32;
typedef __attribute__((ext_vector_type(8))) short bf16x8;
typedef __attribute__((ext_vector_type(4))) float f32x4;

__device__ __forceinline__ u16 f2b(float f) {
    // round-to-nearest-even fp32 -> bf16
    u32 x = __float_as_uint(f);
    u32 r = (x + 0x7fffu + ((x >> 16) & 1u)) >> 16;
    return (u16)r;
}
__device__ __forceinline__ float b2f(u16 u) {
    return __uint_as_float(((u32)u) << 16);
}
__device__ __forceinline__ float fast_tanh(float x) {
    x = fminf(fmaxf(x, -15.f), 15.f);
    float e = __expf(2.f * x);
    return (e - 1.f) / (e + 1.f);
}
// async global->LDS 16B per lane; LDS dest = wave-uniform base + lane*16
__device__ __forceinline__ void async_copy16(const u16* gp, u16* lp) {
    __builtin_amdgcn_global_load_lds(
        (const __attribute__((address_space(1))) unsigned int*)gp,
        (__attribute__((address_space(3))) unsigned int*)lp, 16, 0, 0);
}

#define WAITV(N) do { asm volatile("s_waitcnt vmcnt(" #N ")" ::: "memory"); \
                      __builtin_amdgcn_sched_barrier(0); } while (0)
#define MF(a_, b_, c_) __builtin_amdgcn_mfma_f32_16x16x32_bf16(a_, b_, c_, 0, 0, 0)

// ---------------- kernel 1: U_w [k][n] fp32 -> U_wT [n][k] bf16 ----------------
__global__ __launch_bounds__(256) void k_transpose_uw(const float* __restrict__ Uw,
                                                      u16* __restrict__ UwT) {
    __shared__ float tile[64][65];
    int n0 = blockIdx.x * 64, k0 = blockIdx.y * 64;
    int c = threadIdx.x & 63, r0 = threadIdx.x >> 6;   // r0 in 0..3
#pragma unroll
    for (int i = 0; i < 64; i += 4)
        tile[r0 + i][c] = Uw[(size_t)(k0 + r0 + i) * UU + n0 + c];
    __syncthreads();
#pragma unroll
    for (int i = 0; i < 64; i += 4)
        UwT[(size_t)(n0 + r0 + i) * UU + k0 + c] = f2b(tile[c][r0 + i]);
}

// ---------------- kernel 2: h fp32 -> bf16 ----------------
__global__ __launch_bounds__(256) void k_convert_h(const float* __restrict__ src,
                                                   u16* __restrict__ dst) {
    size_t i = ((size_t)blockIdx.x * 256 + threadIdx.x) * 8;
    float4 f0 = *(const float4*)(src + i);
    float4 f1 = *(const float4*)(src + i + 4);
    u16 t[8];
    t[0] = f2b(f0.x); t[1] = f2b(f0.y); t[2] = f2b(f0.z); t[3] = f2b(f0.w);
    t[4] = f2b(f1.x); t[5] = f2b(f1.y); t[6] = f2b(f1.z); t[7] = f2b(f1.w);
    *(uint4*)(dst + i) = *(uint4*)t;
}

// ---------------- kernel 3: Ws = s_prev @ W_w + W_b (fp32), split-K atomic ----
__global__ __launch_bounds__(256) void k_ws(const float* __restrict__ sp,
                                            const float* __restrict__ Ww,
                                            const float* __restrict__ Wb,
                                            float* __restrict__ Ws) {
    int u = blockIdx.x * 256 + threadIdx.x;   // 0..1023
    int b = blockIdx.y;
    int k0 = blockIdx.z * 256;
    const float* sprow = sp + (size_t)b * UU + k0;
    float acc = (blockIdx.z == 0) ? Wb[u] : 0.f;
#pragma unroll 4
    for (int k = 0; k < 256; ++k)
        acc = fmaf(sprow[k], Ww[(size_t)(k0 + k) * UU + u], acc);
    atomicAdd(&Ws[(size_t)b * UU + u], acc);
}

// ---------------- kernel 4: 256^2 8-phase deep-pipelined GEMM + tanh*V_w ------
// m201-style schedule: BK=64 split into 2 K-halves (256 rows x 32 cols, 16 KB),
// double-buffered (128 KB LDS). Per K-tile: 4 phases = (m-half x k-step)
// quadrants of 16 MFMA; each phase stages one half-tile (2 global_load_lds/thr);
// counted vmcnt(8) gates only where the ledger requires; raw s_barrier (no
// drain). setprio(1) around each MFMA cluster.
//
// Stage/consume ledger (per wave, loads in issue order; 2 loads per half-tile):
//   group g phases stage: P0:A(g+1,k1)  P1:B(g+1,k1)  P2:A(g+2,k0)  P3:B(g+2,k0)
//   reads: P0/P1 <- {A,B}(g,k0);  P2/P3 <- {A,B}(g,k1)
//   gate at end-P1 (covers P2/P3 reads): need A/B(g,k1) = staged 4 HT ago -> vmcnt(8)
//   gate at end-P3 (covers next P0/P1):  need A/B(g+1,k0) = 4 HT ago       -> vmcnt(8)
//   buffer overwrite safety: each half staged only after its previous tenant's
//   last ds_read completed behind an earlier barrier (see per-stage comments).
//   Tail: g=14 stages P0,P1 only (end-P3 gate -> vmcnt(4)); g=15 stages none
//   (end-P1 gate -> vmcnt(0)).
__global__ __launch_bounds__(512, 2) void k_gemm256(const u16* __restrict__ A,
                                                    const u16* __restrict__ UwT,
                                                    const float* __restrict__ Ws,
                                                    const float* __restrict__ Ub,
                                                    const float* __restrict__ Vw,
                                                    float* __restrict__ scp) {
    // [buf][khalf][256 rows x 32 bf16]  (rows of 64 B = 4 chunks of 16 B)
    __shared__ __align__(16) u16 As[2][2][8192];
    __shared__ __align__(16) u16 Bs[2][2][8192];
    const int tid  = threadIdx.x;
    const int lane = tid & 63;
    const int wave = tid >> 6;            // 0..7
    const int wm = wave >> 2;             // 0..1 : M half (128 rows)
    const int wn = wave & 3;              // 0..3 : N quarter (64 cols)
    const int quad = lane >> 4, l15 = lane & 15;

    const int bid = blockIdx.x;
    const int xcd = bid & 7;
    const int li  = bid >> 3;             // 0..255 per XCD
    const int mt  = xcd * 64 + (li >> 2); // 0..511
    const int nt  = li & 3;               // 0..3
    const size_t m0 = (size_t)mt * 256;
    const int n0  = nt * 256;

    // staging lane geometry: per global_load_lds a wave writes one 16-row x
    // 4-chunk group (1 KB), linear dest; source pre-swizzled so LDS slot s of
    // row ri holds global chunk s ^ ((ri>>1)&3)  (2 lanes/bank on read = free).
    const int srow   = lane >> 2;                       // 0..15
    const int schunk = (lane & 3) ^ ((srow >> 1) & 3);  // 16B chunk to fetch
    const size_t lane_src = (size_t)srow * UU + (size_t)schunk * 8;
    const int gA = wave * 2;              // this wave's two groups per half-tile

    // fragment LDS offsets (u16 units) within a K-half
    int offA[2][4], offB[4];
#pragma unroll
    for (int mh = 0; mh < 2; ++mh)
#pragma unroll
        for (int q = 0; q < 4; ++q) {
            int r = wm * 128 + mh * 64 + q * 16 + l15;
            offA[mh][q] = r * 32 + ((quad ^ ((r >> 1) & 3)) << 3);
        }
#pragma unroll
    for (int ni = 0; ni < 4; ++ni) {
        int r = wn * 64 + ni * 16 + l15;
        offB[ni] = r * 32 + ((quad ^ ((r >> 1) & 3)) << 3);
    }

    f32x4 acc[8][4];
#pragma unroll
    for (int i = 0; i < 8; ++i)
#pragma unroll
        for (int j = 0; j < 4; ++j) acc[i][j] = (f32x4){0.f, 0.f, 0.f, 0.f};

    const u16* Abase = A + m0 * UU;
    const u16* Bbase = UwT + (size_t)n0 * UU;

#define STAGE_A(KT, KH) do {                                                   \
        const u16* _s = Abase + (size_t)(gA * 16) * UU                         \
                        + (size_t)((KT) * 64 + (KH) * 32) + lane_src;          \
        u16* _d = &As[(KT) & 1][KH][gA * 512];                                 \
        async_copy16(_s, _d);                                                  \
        async_copy16(_s + (size_t)(16 * UU), _d + 512);                        \
    } while (0)
#define STAGE_B(KT, KH) do {                                                   \
        const u16* _s = Bbase + (size_t)(gA * 16) * UU                         \
                        + (size_t)((KT) * 64 + (KH) * 32) + lane_src;          \
        u16* _d = &Bs[(KT) & 1][KH][gA * 512];                                 \
        async_copy16(_s, _d);                                                  \
        async_copy16(_s + (size_t)(16 * UU), _d + 512);                        \
    } while (0)

// one phase: {ds_read subtile || stage 1 half-tile} -> barrier -> lgkmcnt(0)
// -> 16 MFMA (setprio) -> [gate] -> barrier
#define PHASE(MH, KS, STAGE_STMT, TAILGATE_STMT)                               \
    do {                                                                       \
        const u16* _ah = &As[buf][KS][0];                                      \
        if ((MH) == 0) {                                                       \
            const u16* _bh = &Bs[buf][KS][0];                                  \
            b[0] = *(const bf16x8*)(_bh + offB[0]);                            \
            b[1] = *(const bf16x8*)(_bh + offB[1]);                            \
            b[2] = *(const bf16x8*)(_bh + offB[2]);                            \
            b[3] = *(const bf16x8*)(_bh + offB[3]);                            \
        }                                                                      \
        bf16x8 _a0 = *(const bf16x8*)(_ah + offA[MH][0]);                      \
        bf16x8 _a1 = *(const bf16x8*)(_ah + offA[MH][1]);                      \
        bf16x8 _a2 = *(const bf16x8*)(_ah + offA[MH][2]);                      \
        bf16x8 _a3 = *(const bf16x8*)(_ah + offA[MH][3]);                      \
        STAGE_STMT;                                                            \
        asm volatile("s_waitcnt lgkmcnt(0)" ::: "memory");                     \
        __builtin_amdgcn_sched_barrier(0);                                     \
        __builtin_amdgcn_s_barrier();                                          \
        __builtin_amdgcn_sched_barrier(0);                                     \
        __builtin_amdgcn_s_setprio(1);                                         \
        acc[(MH)*4+0][0] = MF(_a0, b[0], acc[(MH)*4+0][0]);                    \
        acc[(MH)*4+0][1] = MF(_a0, b[1], acc[(MH)*4+0][1]);                    \
        acc[(MH)*4+0][2] = MF(_a0, b[2], acc[(MH)*4+0][2]);                    \
        acc[(MH)*4+0][3] = MF(_a0, b[3], acc[(MH)*4+0][3]);                    \
        acc[(MH)*4+1][0] = MF(_a1, b[0], acc[(MH)*4+1][0]);                    \
        acc[(MH)*4+1][1] = MF(_a1, b[1], acc[(MH)*4+1][1]);                    \
        acc[(MH)*4+1][2] = MF(_a1, b[2], acc[(MH)*4+1][2]);                    \
        acc[(MH)*4+1][3] = MF(_a1, b[3], acc[(MH)*4+1][3]);                    \
        acc[(MH)*4+2][0] = MF(_a2, b[0], acc[(MH)*4+2][0]);                    \
        acc[(MH)*4+2][1] = MF(_a2, b[1], acc[(MH)*4+2][1]);                    \
        acc[(MH)*4+2][2] = MF(_a2, b[2], acc[(MH)*4+2][2]);                    \
        acc[(MH)*4+2][3] = MF(_a2, b[3], acc[(MH)*4+2][3]);                    \
        acc[(MH)*4+3][0] = MF(_a3, b[0], acc[(MH)*4+3][0]);                    \
        acc[(MH)*4+3][1] = MF(_a3, b[1], acc[(MH)*4+3][1]);                    \
        acc[(MH)*4+3][2] = MF(_a3, b[2], acc[(MH)*4+3][2]);                    \
        acc[(MH)*4+3][3] = MF(_a3, b[3], acc[(MH)*4+3][3]);                    \
        __builtin_amdgcn_s_setprio(0);                                         \
        __builtin_amdgcn_sched_barrier(0);                                     \
        TAILGATE_STMT;                                                         \
        __builtin_amdgcn_s_barrier();                                          \
        __builtin_amdgcn_sched_barrier(0);                                     \
    } while (0)

#define GROUP(G, S0, S1, S2, S3, GATE1, GATE3)                                 \
    do {                                                                       \
        const int buf = (G) & 1;                                               \
        bf16x8 b[4];                                                           \
        PHASE(0, 0, S0, (void)0);                                              \
        PHASE(1, 0, S1, GATE1);                                                \
        PHASE(0, 1, S2, (void)0);                                              \
        PHASE(1, 1, S3, GATE3);                                                \
    } while (0)

    // prologue: 6 half-tiles in flight (12 loads/thread), matching the
    // steady-state ledger. Gate: first 2 half-tiles landed -> vmcnt(8).
    STAGE_A(0, 0); STAGE_B(0, 0);
    STAGE_A(0, 1); STAGE_B(0, 1);
    STAGE_A(1, 0); STAGE_B(1, 0);
    WAITV(8);
    __builtin_amdgcn_s_barrier();
    __builtin_amdgcn_sched_barrier(0);

#pragma unroll 2
    for (int g = 0; g < 14; ++g) {
        GROUP(g, STAGE_A(g + 1, 1), STAGE_B(g + 1, 1),
                 STAGE_A(g + 2, 0), STAGE_B(g + 2, 0),
                 WAITV(8), WAITV(8));
    }
    GROUP(14, STAGE_A(15, 1), STAGE_B(15, 1), (void)0, (void)0,
              WAITV(8), WAITV(4));
    GROUP(15, (void)0, (void)0, (void)0, (void)0,
              WAITV(0), (void)0);

#undef GROUP
#undef PHASE
#undef STAGE_A
#undef STAGE_B

    // ---- epilogue: score partial = sum_n tanh(acc + Ws[b][n] + Ub[n]) * Vw[n] ----
    const int bidx = (int)(m0 >> 11);            // 256-row m-tile lies in one batch
    const float* wsrow = Ws + (size_t)bidx * UU;
    float wsv[4], ubv[4], vwv[4];
#pragma unroll
    for (int ni = 0; ni < 4; ++ni) {
        int ng = n0 + wn * 64 + ni * 16 + l15;
        wsv[ni] = wsrow[ng];
        ubv[ni] = Ub[ng];
        vwv[ni] = Vw[ng];
    }
#pragma unroll
    for (int mi = 0; mi < 8; ++mi) {
#pragma unroll
        for (int r = 0; r < 4; ++r) {
            float v = 0.f;
#pragma unroll
            for (int ni = 0; ni < 4; ++ni) {
                float x = acc[mi][ni][r] + wsv[ni] + ubv[ni];
                v = fmaf(fast_tanh(x), vwv[ni], v);
            }
#pragma unroll
            for (int off = 1; off < 16; off <<= 1)
                v += __shfl_xor(v, off, 64);
            if (l15 == 0) {
                size_t mg = m0 + wm * 128 + mi * 16 + quad * 4 + r;
                scp[mg * 16 + nt * 4 + wn] = v;
            }
        }
    }
}

// ---------------- kernel 4b: fp32-input fallback (ws too small for hbf) -------
__global__ __launch_bounds__(256) void k_gemm_f32(const float* __restrict__ Aptr,
                                                  const u16* __restrict__ UwT,
                                                  const float* __restrict__ Ws,
                                                  const float* __restrict__ Ub,
                                                  const float* __restrict__ Vw,
                                                  float* __restrict__ scp) {
    __shared__ __align__(16) u16 As[128][72];
    __shared__ __align__(16) u16 Bs[128][72];
    const int tid  = threadIdx.x;
    const int lane = tid & 63;
    const int wave = tid >> 6;
    const int wm = wave >> 1, wn = wave & 1;
    const int quad = lane >> 4, l15 = lane & 15;
    const int nt = blockIdx.x;
    const int n0 = nt * 128;
    const size_t m0 = (size_t)blockIdx.y * 128;

    f32x4 acc[4][4];
#pragma unroll
    for (int i = 0; i < 4; ++i)
#pragma unroll
        for (int j = 0; j < 4; ++j) acc[i][j] = (f32x4){0.f, 0.f, 0.f, 0.f};

    const int sr = tid >> 3;
    const int sc = (tid & 7) * 8;

    for (int kk = 0; kk < UU; kk += 64) {
#pragma unroll
        for (int i = 0; i < 4; ++i) {
            int r = sr + i * 32;
            const float4* p = (const float4*)(Aptr + (m0 + r) * UU + kk + sc);
            float4 f0 = p[0], f1 = p[1];
            u16 t[8];
            t[0] = f2b(f0.x); t[1] = f2b(f0.y); t[2] = f2b(f0.z); t[3] = f2b(f0.w);
            t[4] = f2b(f1.x); t[5] = f2b(f1.y); t[6] = f2b(f1.z); t[7] = f2b(f1.w);
            *(uint4*)(&As[r][sc]) = *(uint4*)t;
        }
#pragma unroll
        for (int i = 0; i < 4; ++i) {
            int r = sr + i * 32;
            uint4 v = *(const uint4*)(UwT + (size_t)(n0 + r) * UU + kk + sc);
            *(uint4*)(&Bs[r][sc]) = v;
        }
        __syncthreads();
#pragma unroll
        for (int k2 = 0; k2 < 64; k2 += 32) {
            bf16x8 a[4], b[4];
#pragma unroll
            for (int mi = 0; mi < 4; ++mi)
                a[mi] = *(const bf16x8*)(&As[wm * 64 + mi * 16 + l15][k2 + quad * 8]);
#pragma unroll
            for (int ni = 0; ni < 4; ++ni)
                b[ni] = *(const bf16x8*)(&Bs[wn * 64 + ni * 16 + l15][k2 + quad * 8]);
#pragma unroll
            for (int mi = 0; mi < 4; ++mi)
#pragma unroll
                for (int ni = 0; ni < 4; ++ni)
                    acc[mi][ni] = __builtin_amdgcn_mfma_f32_16x16x32_bf16(
                        a[mi], b[ni], acc[mi][ni], 0, 0, 0);
        }
        __syncthreads();
    }

    const int bidx = (int)(m0 >> 11);
    const float* wsrow = Ws + (size_t)bidx * UU;
    float wsv[4], ubv[4], vwv[4];
#pragma unroll
    for (int ni = 0; ni < 4; ++ni) {
        int ng = n0 + wn * 64 + ni * 16 + l15;
        wsv[ni] = wsrow[ng];
        ubv[ni] = Ub[ng];
        vwv[ni] = Vw[ng];
    }
#pragma unroll
    for (int mi = 0; mi < 4; ++mi) {
#pragma unroll
        for (int r = 0; r < 4; ++r) {
            float v = 0.f;
#pragma unroll
            for (int ni = 0; ni < 4; ++ni) {
                float x = acc[mi][ni][r] + wsv[ni] + ubv[ni];
                v = fmaf(fast_tanh(x), vwv[ni], v);
            }
#pragma unroll
            for (int off = 1; off < 16; off <<= 1)
                v += __shfl_xor(v, off, 64);
            if (l15 == 0) {
                size_t mg = m0 + wm * 64 + mi * 16 + quad * 4 + r;
                scp[mg * 16 + nt * 2 + wn] = v;
            }
        }
    }
}

// ---------------- kernel 5: softmax over S per batch ----------------
__global__ __launch_bounds__(256) void k_softmax(const float* __restrict__ scp,
                                                 float* __restrict__ wout) {
    int b = blockIdx.x, t = threadIdx.x;
    __shared__ float red[256];
    float sc[8];
    float lmax = -1e30f;
#pragma unroll
    for (int i = 0; i < 8; ++i) {
        int s = t + i * 256;
        const float4* p = (const float4*)(scp + ((size_t)b * SS + s) * 16);
        float4 a = p[0], c = p[1], d = p[2], e = p[3];
        float v = (a.x + a.y + a.z + a.w) + (c.x + c.y + c.z + c.w) +
                  (d.x + d.y + d.z + d.w) + (e.x + e.y + e.z + e.w);
        sc[i] = v;
        lmax = fmaxf(lmax, v);
    }
    red[t] = lmax;
    __syncthreads();
    for (int o = 128; o > 0; o >>= 1) {
        if (t < o) red[t] = fmaxf(red[t], red[t + o]);
        __syncthreads();
    }
    float mx = red[0];
    __syncthreads();
    float lsum = 0.f;
#pragma unroll
    for (int i = 0; i < 8; ++i) {
        sc[i] = __expf(sc[i] - mx);
        lsum += sc[i];
    }
    red[t] = lsum;
    __syncthreads();
    for (int o = 128; o > 0; o >>= 1) {
        if (t < o) red[t] += red[t + o];
        __syncthreads();
    }
    float inv = 1.f / red[0];
#pragma unroll
    for (int i = 0; i < 8; ++i)
        wout[(size_t)b * SS + t + i * 256] = sc[i] * inv;
}

// ---------------- kernel 6: context = sum_s w[b][s] * h[b][s][:] ----------------
template <bool HBF16>
__global__ __launch_bounds__(256) void k_context(const void* __restrict__ hptr,
                                                 const float* __restrict__ w,
                                                 float* __restrict__ ctx) {
    int b = blockIdx.y;
    int s0 = blockIdx.x * 128;
    int u = threadIdx.x * 4;
    const float* wrow = w + (size_t)b * SS + s0;
    float a0 = 0.f, a1 = 0.f, a2 = 0.f, a3 = 0.f;
    for (int i = 0; i < 128; ++i) {
        float wv = wrow[i];
        size_t base = ((size_t)b * SS + s0 + i) * UU + u;
        if (HBF16) {
            ushort4 hv = *(const ushort4*)((const u16*)hptr + base);
            a0 = fmaf(wv, b2f(hv.x), a0);
            a1 = fmaf(wv, b2f(hv.y), a1);
            a2 = fmaf(wv, b2f(hv.z), a2);
            a3 = fmaf(wv, b2f(hv.w), a3);
        } else {
            float4 hv = *(const float4*)((const float*)hptr + base);
            a0 = fmaf(wv, hv.x, a0);
            a1 = fmaf(wv, hv.y, a1);
            a2 = fmaf(wv, hv.z, a2);
            a3 = fmaf(wv, hv.w, a3);
        }
    }
    atomicAdd(&ctx[(size_t)b * UU + u + 0], a0);
    atomicAdd(&ctx[(size_t)b * UU + u + 1], a1);
    atomicAdd(&ctx[(size_t)b * UU + u + 2], a2);
    atomicAdd(&ctx[(size_t)b * UU + u + 3], a3);
}

extern "C" void kernel_launch(void* const* d_in, const int* in_sizes, int n_in,
                              void* d_out, int out_size, void* d_ws, size_t ws_size,
                              hipStream_t stream) {
    const float* s_prev = (const float*)d_in[0];
    const float* h      = (const float*)d_in[1];
    const float* Ww     = (const float*)d_in[2];
    const float* Wb     = (const float*)d_in[3];
    const float* Uw     = (const float*)d_in[4];
    const float* Ub     = (const float*)d_in[5];
    const float* Vw     = (const float*)d_in[6];
    // d_in[7] = V_b: softmax(x + c) == softmax(x) -> V_b cancels in both outputs.

    float* out = (float*)d_out;                 // [0,65536): context  [65536,196608): weights
    char* ws = (char*)d_ws;

    // workspace layout
    u16*   UwT = (u16*)ws;                                        // 2 MB
    float* Ws  = (float*)(ws + (size_t)(2 << 20));                // 256 KB
    float* scp = (float*)(ws + (size_t)(2 << 20) + (256 << 10));  // 131072*16*4 = 8 MB
    size_t offH = (size_t)(2 << 20) + (256 << 10) + ((size_t)8 << 20);
    u16*   hbf = (u16*)(ws + offH);
    const size_t hBytes = (size_t)MM * UU * 2;  // 256 MB
    const bool useBf16 = (ws_size >= offH + hBytes);

    // zero atomically-accumulated buffers
    hipMemsetAsync(out, 0, (size_t)BB * UU * sizeof(float), stream);
    hipMemsetAsync(Ws, 0, (size_t)BB * UU * sizeof(float), stream);

    k_transpose_uw<<<dim3(16, 16), 256, 0, stream>>>(Uw, UwT);
    k_ws<<<dim3(4, BB, 4), 256, 0, stream>>>(s_prev, Ww, Wb, Ws);

    if (useBf16) {
        k_convert_h<<<(MM * (UU / 8)) / 256, 256, 0, stream>>>(h, hbf);
        k_gemm256<<<2048, 512, 0, stream>>>(hbf, UwT, Ws, Ub, Vw, scp);
    } else {
        k_gemm_f32<<<dim3(8, MM / 128), 256, 0, stream>>>(h, UwT, Ws, Ub, Vw, scp);
    }

    k_softmax<<<BB, 256, 0, stream>>>(scp, out + (size_t)BB * UU);

    if (useBf16)
        k_context<true><<<dim3(16, BB), 256, 0, stream>>>(hbf, out + (size_t)BB * UU, out);
    else
        k_context<false><<<dim3(16, BB), 256, 0, stream>>>(h, out + (size_t)BB * UU, out);
}

// Round 3
// 1160.905 us; speedup vs baseline: 1.0850x; 1.0260x over previous
//
#include <hip/hip_runtime.h>

// Problem constants (fixed by reference): B=64, S=2048, UNITS=1024
#define BB   64
#define SS   2048
#define UU   1024
#define MM   (BB * SS)          // 131072 rows of the big GEMM

typedef unsigned short u16;
typedef unsigned int   u32;
typedef __attribute__((ext_vector_type(8))) short bf16x8;
typedef __attribute__((ext_vector_type(4))) float f32x4;

__device__ __forceinline__ u16 f2b(float f) {
    // round-to-nearest-even fp32 -> bf16
    u32 x = __float_as_uint(f);
    u32 r = (x + 0x7fffu + ((x >> 16) & 1u)) >> 16;
    return (u16)r;
}
__device__ __forceinline__ float b2f(u16 u) {
    return __uint_as_float(((u32)u) << 16);
}
__device__ __forceinline__ float fast_tanh(float x) {
    x = fminf(fmaxf(x, -15.f), 15.f);
    float e = __expf(2.f * x);
    return (e - 1.f) / (e + 1.f);
}
// async global->LDS 16B per lane; LDS dest = wave-uniform base + lane*16
__device__ __forceinline__ void async_copy16(const u16* gp, u16* lp) {
    __builtin_amdgcn_global_load_lds(
        (const __attribute__((address_space(1))) unsigned int*)gp,
        (__attribute__((address_space(3))) unsigned int*)lp, 16, 0, 0);
}

// counted vmcnt gate: "memory" clobber orders LDS reads; NO sched_barrier
// (m141: order-pinning regresses 42%)
#define WAITV(N) asm volatile("s_waitcnt vmcnt(" #N ")" ::: "memory")
// post-barrier LDS drain; sched_barrier required (rule 18: hipcc hoists
// register-only MFMA past inline-asm lgkmcnt)
#define LGKM0 do { asm volatile("s_waitcnt lgkmcnt(0)" ::: "memory"); \
                   __builtin_amdgcn_sched_barrier(0); } while (0)
#define BAR  __builtin_amdgcn_s_barrier()
#define MF(a_, b_, c_) __builtin_amdgcn_mfma_f32_16x16x32_bf16(a_, b_, c_, 0, 0, 0)

// ---------------- kernel 1: U_w [k][n] fp32 -> U_wT [n][k] bf16 ----------------
__global__ __launch_bounds__(256) void k_transpose_uw(const float* __restrict__ Uw,
                                                      u16* __restrict__ UwT) {
    __shared__ float tile[64][65];
    int n0 = blockIdx.x * 64, k0 = blockIdx.y * 64;
    int c = threadIdx.x & 63, r0 = threadIdx.x >> 6;   // r0 in 0..3
#pragma unroll
    for (int i = 0; i < 64; i += 4)
        tile[r0 + i][c] = Uw[(size_t)(k0 + r0 + i) * UU + n0 + c];
    __syncthreads();
#pragma unroll
    for (int i = 0; i < 64; i += 4)
        UwT[(size_t)(n0 + r0 + i) * UU + k0 + c] = f2b(tile[c][r0 + i]);
}

// ---------------- kernel 2: h fp32 -> bf16 ----------------
__global__ __launch_bounds__(256) void k_convert_h(const float* __restrict__ src,
                                                   u16* __restrict__ dst) {
    size_t i = ((size_t)blockIdx.x * 256 + threadIdx.x) * 8;
    float4 f0 = *(const float4*)(src + i);
    float4 f1 = *(const float4*)(src + i + 4);
    u16 t[8];
    t[0] = f2b(f0.x); t[1] = f2b(f0.y); t[2] = f2b(f0.z); t[3] = f2b(f0.w);
    t[4] = f2b(f1.x); t[5] = f2b(f1.y); t[6] = f2b(f1.z); t[7] = f2b(f1.w);
    *(uint4*)(dst + i) = *(uint4*)t;
}

// ---------------- kernel 3: Ws = s_prev @ W_w + W_b (fp32), split-K atomic ----
__global__ __launch_bounds__(256) void k_ws(const float* __restrict__ sp,
                                            const float* __restrict__ Ww,
                                            const float* __restrict__ Wb,
                                            float* __restrict__ Ws) {
    int u = blockIdx.x * 256 + threadIdx.x;   // 0..1023
    int b = blockIdx.y;
    int k0 = blockIdx.z * 256;
    const float* sprow = sp + (size_t)b * UU + k0;
    float acc = (blockIdx.z == 0) ? Wb[u] : 0.f;
#pragma unroll 4
    for (int k = 0; k < 256; ++k)
        acc = fmaf(sprow[k], Ww[(size_t)(k0 + k) * UU + u], acc);
    atomicAdd(&Ws[(size_t)b * UU + u], acc);
}

// ---------------- kernel 4: 256^2 8-phase (m201-style) GEMM + tanh*V_w --------
// BK=64, full-K-tile double buffer (2 x 32KB x {A,B} = 128 KB LDS).
// 8 waves (2M x 4N); per-wave rows remapped so phase reads align with staged
// row-halves:  A row(mi) = mi*32 + wm*16 + l15   (mi 0..7)
//              B row(ni) = ni*64 + wn*16 + l15   (ni 0..3)
// Phases per K-tile t (buf = t&1), m201 template:
//   P00: ds A-h0 (8) + B-h0 (4) | stage Ah0(t+1) | bar | lgkm0 | 16 MFMA | G2 vmcnt(2) | bar
//   P01: ds B-h1 (4)            | stage Ah1(t+1) | bar | lgkm0 | 16 MFMA |              bar
//   P10: ds A-h1 (8)            | stage Bh0(t+1) | bar | lgkm0 | 16 MFMA |              bar
//   P11: (0 reads)              | stage Bh1(t+1) | bar |         16 MFMA | G1 vmcnt(2) | bar
// Gates (per-wave counters made collective by the barrier that follows):
//   G1 end-P11(t): outstanding [Ah0',Ah1',Bh0',Bh1'] (8 instr) -> vmcnt(2):
//       Ah0',Ah1',Bh0' landed  (P00/P10 of t+1 read them)
//   G2 end-P00(t): outstanding [Bh1(t), Ah0(t+1)] (4) -> vmcnt(2):
//       Bh1(t) landed (P01 reads it)
// Leads: A halves 3-4 phases (HBM/L3-resident), B halves 2 phases (L2-hot).
__global__ __launch_bounds__(512, 2) void k_gemm256(const u16* __restrict__ A,
                                                    const u16* __restrict__ UwT,
                                                    const float* __restrict__ Ws,
                                                    const float* __restrict__ Ub,
                                                    const float* __restrict__ Vw,
                                                    float* __restrict__ scp) {
    __shared__ __align__(16) u16 As[2][16384];   // [buf][256 rows x 64 bf16]
    __shared__ __align__(16) u16 Bs[2][16384];
    const int tid  = threadIdx.x;
    const int lane = tid & 63;
    const int wave = tid >> 6;            // 0..7
    const int wm = wave >> 2;             // 0..1
    const int wn = wave & 3;              // 0..3
    const int quad = lane >> 4, l15 = lane & 15;

    const int bid = blockIdx.x;
    const int xcd = bid & 7;
    const int li  = bid >> 3;             // 0..255 per XCD
    const int mt  = xcd * 64 + (li >> 2); // 0..511
    const int nt  = li & 3;               // 0..3
    const size_t m0 = (size_t)mt * 256;
    const int n0  = nt * 256;

    // staging lane geometry: one instr = 1KB = 8 rows x 128B, linear dest.
    // LDS chunk p of row r holds global chunk p ^ (r&7); source pre-swizzled.
    const int srow8  = lane >> 3;                       // 0..7
    const int schunk = (lane & 7) ^ srow8;              // 16B chunk to fetch
    const size_t lane_src = (size_t)srow8 * UU + (size_t)schunk * 8;

    // fragment LDS offsets (u16 elems) within a half (8192 elems); ks1 = ^32
    const int cw = (quad ^ (l15 & 7)) << 3;             // swizzled chunk byte/2
    int offA[4], offB[2];
#pragma unroll
    for (int j = 0; j < 4; ++j)
        offA[j] = (j * 32 + wm * 16 + l15) * 64 + cw;   // rows 0..127 of a half
#pragma unroll
    for (int j = 0; j < 2; ++j)
        offB[j] = (j * 64 + wn * 16 + l15) * 64 + cw;

    f32x4 acc[8][4];
#pragma unroll
    for (int i = 0; i < 8; ++i)
#pragma unroll
        for (int j = 0; j < 4; ++j) acc[i][j] = (f32x4){0.f, 0.f, 0.f, 0.f};

    const u16* Abase = A + m0 * UU;
    const u16* Bbase = UwT + (size_t)n0 * UU;

    bf16x8 a[4][2], b[4][2];

#define STAGE_A(KT, H) do {                                                    \
        const u16* _s = Abase + (size_t)((H) * 128 + wave * 16) * UU           \
                        + (size_t)((KT) * 64) + lane_src;                      \
        u16* _d = &As[(KT) & 1][((H) * 128 + wave * 16) * 64];                 \
        async_copy16(_s, _d);                                                  \
        async_copy16(_s + (size_t)(8 * UU), _d + 512);                         \
    } while (0)
#define STAGE_B(KT, H) do {                                                    \
        const u16* _s = Bbase + (size_t)((H) * 128 + wave * 16) * UU           \
                        + (size_t)((KT) * 64) + lane_src;                      \
        u16* _d = &Bs[(KT) & 1][((H) * 128 + wave * 16) * 64];                 \
        async_copy16(_s, _d);                                                  \
        async_copy16(_s + (size_t)(8 * UU), _d + 512);                         \
    } while (0)
// read A-half MH into a[0..3][0..1] (8 ds_read_b128)
#define READ_A(BUF, MH) do {                                                   \
        const u16* _p = &As[BUF][(MH) * 8192];                                 \
        _Pragma("unroll")                                                      \
        for (int _j = 0; _j < 4; ++_j) {                                       \
            a[_j][0] = *(const bf16x8*)(_p + offA[_j]);                        \
            a[_j][1] = *(const bf16x8*)(_p + (offA[_j] ^ 32));                 \
        }                                                                      \
    } while (0)
// read B-half NH into b[NH*2 .. NH*2+1][0..1] (4 ds_read_b128)
#define READ_B(BUF, NH) do {                                                   \
        const u16* _p = &Bs[BUF][(NH) * 8192];                                 \
        _Pragma("unroll")                                                      \
        for (int _j = 0; _j < 2; ++_j) {                                       \
            b[(NH) * 2 + _j][0] = *(const bf16x8*)(_p + offB[_j]);             \
            b[(NH) * 2 + _j][1] = *(const bf16x8*)(_p + (offB[_j] ^ 32));      \
        }                                                                      \
    } while (0)
#define MMA(MH, NH) do {                                                       \
        __builtin_amdgcn_s_setprio(1);                                         \
        _Pragma("unroll")                                                      \
        for (int _j = 0; _j < 4; ++_j)                                         \
            _Pragma("unroll")                                                  \
            for (int _n = 0; _n < 2; ++_n) {                                   \
                acc[(MH)*4+_j][(NH)*2+_n] =                                    \
                    MF(a[_j][0], b[(NH)*2+_n][0], acc[(MH)*4+_j][(NH)*2+_n]);  \
                acc[(MH)*4+_j][(NH)*2+_n] =                                    \
                    MF(a[_j][1], b[(NH)*2+_n][1], acc[(MH)*4+_j][(NH)*2+_n]);  \
            }                                                                  \
        __builtin_amdgcn_s_setprio(0);                                         \
    } while (0)

    // prologue: K-tile 0's 4 halves in ledger order
    STAGE_A(0, 0); STAGE_A(0, 1); STAGE_B(0, 0); STAGE_B(0, 1);
    WAITV(2);                 // Ah0,Ah1,Bh0 landed; Bh1 may be in flight
    BAR;

#pragma unroll 2
    for (int t = 0; t < 15; ++t) {
        const int buf = t & 1;
        // P00
        READ_A(buf, 0); READ_B(buf, 0);
        STAGE_A(t + 1, 0);
        BAR; LGKM0;
        MMA(0, 0);
        WAITV(2);             // G2: Bh1(t) landed for P01
        BAR;
        // P01
        READ_B(buf, 1);
        STAGE_A(t + 1, 1);
        BAR; LGKM0;
        MMA(0, 1);
        BAR;
        // P10
        READ_A(buf, 1);
        STAGE_B(t + 1, 0);
        BAR; LGKM0;
        MMA(1, 0);
        BAR;
        // P11
        STAGE_B(t + 1, 1);
        BAR;
        MMA(1, 1);
        WAITV(2);             // G1: Ah0',Ah1',Bh0' landed for t+1
        BAR;
    }
    // tail K-tile t=15 (buf=1): no stages
    READ_A(1, 0); READ_B(1, 0);
    BAR; LGKM0;
    MMA(0, 0);
    WAITV(0);                 // drain Bh1(15)
    BAR;
    READ_B(1, 1);
    BAR; LGKM0;
    MMA(0, 1);
    BAR;
    READ_A(1, 1);
    BAR; LGKM0;
    MMA(1, 0);
    MMA(1, 1);

#undef STAGE_A
#undef STAGE_B
#undef READ_A
#undef READ_B
#undef MMA

    // ---- epilogue: score partial = sum_n tanh(acc + Ws[b][n] + Ub[n]) * Vw[n] ----
    const int bidx = (int)(m0 >> 11);            // 256-row m-tile lies in one batch
    const float* wsrow = Ws + (size_t)bidx * UU;
    float wsv[4], ubv[4], vwv[4];
#pragma unroll
    for (int ni = 0; ni < 4; ++ni) {
        int ng = n0 + ni * 64 + wn * 16 + l15;
        wsv[ni] = wsrow[ng];
        ubv[ni] = Ub[ng];
        vwv[ni] = Vw[ng];
    }
#pragma unroll
    for (int mi = 0; mi < 8; ++mi) {
#pragma unroll
        for (int r = 0; r < 4; ++r) {
            float v = 0.f;
#pragma unroll
            for (int ni = 0; ni < 4; ++ni) {
                float x = acc[mi][ni][r] + wsv[ni] + ubv[ni];
                v = fmaf(fast_tanh(x), vwv[ni], v);
            }
#pragma unroll
            for (int off = 1; off < 16; off <<= 1)
                v += __shfl_xor(v, off, 64);
            if (l15 == 0) {
                size_t mg = m0 + mi * 32 + wm * 16 + quad * 4 + r;
                scp[mg * 16 + nt * 4 + wn] = v;
            }
        }
    }
}

// ---------------- kernel 4b: fp32-input fallback (ws too small for hbf) -------
__global__ __launch_bounds__(256) void k_gemm_f32(const float* __restrict__ Aptr,
                                                  const u16* __restrict__ UwT,
                                                  const float* __restrict__ Ws,
                                                  const float* __restrict__ Ub,
                                                  const float* __restrict__ Vw,
                                                  float* __restrict__ scp) {
    __shared__ __align__(16) u16 As[128][72];
    __shared__ __align__(16) u16 Bs[128][72];
    const int tid  = threadIdx.x;
    const int lane = tid & 63;
    const int wave = tid >> 6;
    const int wm = wave >> 1, wn = wave & 1;
    const int quad = lane >> 4, l15 = lane & 15;
    const int nt = blockIdx.x;
    const int n0 = nt * 128;
    const size_t m0 = (size_t)blockIdx.y * 128;

    f32x4 acc[4][4];
#pragma unroll
    for (int i = 0; i < 4; ++i)
#pragma unroll
        for (int j = 0; j < 4; ++j) acc[i][j] = (f32x4){0.f, 0.f, 0.f, 0.f};

    const int sr = tid >> 3;
    const int sc = (tid & 7) * 8;

    for (int kk = 0; kk < UU; kk += 64) {
#pragma unroll
        for (int i = 0; i < 4; ++i) {
            int r = sr + i * 32;
            const float4* p = (const float4*)(Aptr + (m0 + r) * UU + kk + sc);
            float4 f0 = p[0], f1 = p[1];
            u16 t[8];
            t[0] = f2b(f0.x); t[1] = f2b(f0.y); t[2] = f2b(f0.z); t[3] = f2b(f0.w);
            t[4] = f2b(f1.x); t[5] = f2b(f1.y); t[6] = f2b(f1.z); t[7] = f2b(f1.w);
            *(uint4*)(&As[r][sc]) = *(uint4*)t;
        }
#pragma unroll
        for (int i = 0; i < 4; ++i) {
            int r = sr + i * 32;
            uint4 v = *(const uint4*)(UwT + (size_t)(n0 + r) * UU + kk + sc);
            *(uint4*)(&Bs[r][sc]) = v;
        }
        __syncthreads();
#pragma unroll
        for (int k2 = 0; k2 < 64; k2 += 32) {
            bf16x8 a[4], b[4];
#pragma unroll
            for (int mi = 0; mi < 4; ++mi)
                a[mi] = *(const bf16x8*)(&As[wm * 64 + mi * 16 + l15][k2 + quad * 8]);
#pragma unroll
            for (int ni = 0; ni < 4; ++ni)
                b[ni] = *(const bf16x8*)(&Bs[wn * 64 + ni * 16 + l15][k2 + quad * 8]);
#pragma unroll
            for (int mi = 0; mi < 4; ++mi)
#pragma unroll
                for (int ni = 0; ni < 4; ++ni)
                    acc[mi][ni] = __builtin_amdgcn_mfma_f32_16x16x32_bf16(
                        a[mi], b[ni], acc[mi][ni], 0, 0, 0);
        }
        __syncthreads();
    }

    const int bidx = (int)(m0 >> 11);
    const float* wsrow = Ws + (size_t)bidx * UU;
    float wsv[4], ubv[4], vwv[4];
#pragma unroll
    for (int ni = 0; ni < 4; ++ni) {
        int ng = n0 + wn * 64 + ni * 16 + l15;
        wsv[ni] = wsrow[ng];
        ubv[ni] = Ub[ng];
        vwv[ni] = Vw[ng];
    }
#pragma unroll
    for (int mi = 0; mi < 4; ++mi) {
#pragma unroll
        for (int r = 0; r < 4; ++r) {
            float v = 0.f;
#pragma unroll
            for (int ni = 0; ni < 4; ++ni) {
                float x = acc[mi][ni][r] + wsv[ni] + ubv[ni];
                v = fmaf(fast_tanh(x), vwv[ni], v);
            }
#pragma unroll
            for (int off = 1; off < 16; off <<= 1)
                v += __shfl_xor(v, off, 64);
            if (l15 == 0) {
                size_t mg = m0 + wm * 64 + mi * 16 + quad * 4 + r;
                scp[mg * 16 + nt * 2 + wn] = v;
            }
        }
    }
}

// ---------------- kernel 5: softmax over S per batch ----------------
__global__ __launch_bounds__(256) void k_softmax(const float* __restrict__ scp,
                                                 float* __restrict__ wout) {
    int b = blockIdx.x, t = threadIdx.x;
    __shared__ float red[256];
    float sc[8];
    float lmax = -1e30f;
#pragma unroll
    for (int i = 0; i < 8; ++i) {
        int s = t + i * 256;
        const float4* p = (const float4*)(scp + ((size_t)b * SS + s) * 16);
        float4 a = p[0], c = p[1], d = p[2], e = p[3];
        float v = (a.x + a.y + a.z + a.w) + (c.x + c.y + c.z + c.w) +
                  (d.x + d.y + d.z + d.w) + (e.x + e.y + e.z + e.w);
        sc[i] = v;
        lmax = fmaxf(lmax, v);
    }
    red[t] = lmax;
    __syncthreads();
    for (int o = 128; o > 0; o >>= 1) {
        if (t < o) red[t] = fmaxf(red[t], red[t + o]);
        __syncthreads();
    }
    float mx = red[0];
    __syncthreads();
    float lsum = 0.f;
#pragma unroll
    for (int i = 0; i < 8; ++i) {
        sc[i] = __expf(sc[i] - mx);
        lsum += sc[i];
    }
    red[t] = lsum;
    __syncthreads();
    for (int o = 128; o > 0; o >>= 1) {
        if (t < o) red[t] += red[t + o];
        __syncthreads();
    }
    float inv = 1.f / red[0];
#pragma unroll
    for (int i = 0; i < 8; ++i)
        wout[(size_t)b * SS + t + i * 256] = sc[i] * inv;
}

// ---------------- kernel 6: context = sum_s w[b][s] * h[b][s][:] ----------------
template <bool HBF16>
__global__ __launch_bounds__(256) void k_context(const void* __restrict__ hptr,
                                                 const float* __restrict__ w,
                                                 float* __restrict__ ctx) {
    int b = blockIdx.y;
    int s0 = blockIdx.x * 128;
    int u = threadIdx.x * 4;
    const float* wrow = w + (size_t)b * SS + s0;
    float a0 = 0.f, a1 = 0.f, a2 = 0.f, a3 = 0.f;
    for (int i = 0; i < 128; ++i) {
        float wv = wrow[i];
        size_t base = ((size_t)b * SS + s0 + i) * UU + u;
        if (HBF16) {
            ushort4 hv = *(const ushort4*)((const u16*)hptr + base);
            a0 = fmaf(wv, b2f(hv.x), a0);
            a1 = fmaf(wv, b2f(hv.y), a1);
            a2 = fmaf(wv, b2f(hv.z), a2);
            a3 = fmaf(wv, b2f(hv.w), a3);
        } else {
            float4 hv = *(const float4*)((const float*)hptr + base);
            a0 = fmaf(wv, hv.x, a0);
            a1 = fmaf(wv, hv.y, a1);
            a2 = fmaf(wv, hv.z, a2);
            a3 = fmaf(wv, hv.w, a3);
        }
    }
    atomicAdd(&ctx[(size_t)b * UU + u + 0], a0);
    atomicAdd(&ctx[(size_t)b * UU + u + 1], a1);
    atomicAdd(&ctx[(size_t)b * UU + u + 2], a2);
    atomicAdd(&ctx[(size_t)b * UU + u + 3], a3);
}

extern "C" void kernel_launch(void* const* d_in, const int* in_sizes, int n_in,
                              void* d_out, int out_size, void* d_ws, size_t ws_size,
                              hipStream_t stream) {
    const float* s_prev = (const float*)d_in[0];
    const float* h      = (const float*)d_in[1];
    const float* Ww     = (const float*)d_in[2];
    const float* Wb     = (const float*)d_in[3];
    const float* Uw     = (const float*)d_in[4];
    const float* Ub     = (const float*)d_in[5];
    const float* Vw     = (const float*)d_in[6];
    // d_in[7] = V_b: softmax(x + c) == softmax(x) -> V_b cancels in both outputs.

    float* out = (float*)d_out;                 // [0,65536): context  [65536,196608): weights
    char* ws = (char*)d_ws;

    // workspace layout
    u16*   UwT = (u16*)ws;                                        // 2 MB
    float* Ws  = (float*)(ws + (size_t)(2 << 20));                // 256 KB
    float* scp = (float*)(ws + (size_t)(2 << 20) + (256 << 10));  // 131072*16*4 = 8 MB
    size_t offH = (size_t)(2 << 20) + (256 << 10) + ((size_t)8 << 20);
    u16*   hbf = (u16*)(ws + offH);
    const size_t hBytes = (size_t)MM * UU * 2;  // 256 MB
    const bool useBf16 = (ws_size >= offH + hBytes);

    // zero atomically-accumulated buffers
    hipMemsetAsync(out, 0, (size_t)BB * UU * sizeof(float), stream);
    hipMemsetAsync(Ws, 0, (size_t)BB * UU * sizeof(float), stream);

    k_transpose_uw<<<dim3(16, 16), 256, 0, stream>>>(Uw, UwT);
    k_ws<<<dim3(4, BB, 4), 256, 0, stream>>>(s_prev, Ww, Wb, Ws);

    if (useBf16) {
        k_convert_h<<<(MM * (UU / 8)) / 256, 256, 0, stream>>>(h, hbf);
        k_gemm256<<<2048, 512, 0, stream>>>(hbf, UwT, Ws, Ub, Vw, scp);
    } else {
        k_gemm_f32<<<dim3(8, MM / 128), 256, 0, stream>>>(h, UwT, Ws, Ub, Vw, scp);
    }

    k_softmax<<<BB, 256, 0, stream>>>(scp, out + (size_t)BB * UU);

    if (useBf16)
        k_context<true><<<dim3(16, BB), 256, 0, stream>>>(hbf, out + (size_t)BB * UU, out);
    else
        k_context<false><<<dim3(16, BB), 256, 0, stream>>>(h, out + (size_t)BB * UU, out);
}